// Round 6
// baseline (25702.304 us; speedup 1.0000x reference)
//
#include <hip/hip_runtime.h>

// ---------------------------------------------------------------------------
// FusedSparseLMHead: weighted-mean CE over h @ W^T without materializing logits.
//   h: [4096, 2048] f32, W: [65536, 2048] f32, labels: [4096] int, w: [4096] f32
// Round 6: 256x256 tile, BK=32, 2-buffer ring, ONE barrier/K-step, LDS 64 KB
//   (red arrays overlaid) + __launch_bounds__(512,4) -> 2 blocks/CU so
//   cross-block overlap hides the barrier/wait drains (m114 mechanism).
//   64-B-row swizzle: LDS[r][c] = G[r][c ^ ((r>>1)&3)] (chunks of 16 B).
// ---------------------------------------------------------------------------

typedef __attribute__((ext_vector_type(8)))  short bf16x8;
typedef __attribute__((ext_vector_type(16))) float f32x16;
typedef __attribute__((ext_vector_type(8)))  float f32x8;
typedef __attribute__((ext_vector_type(8)))  unsigned short u16x8;

#define N_TOK 4096
#define DIM   2048
#define VOCAB 65536
#define BM    256
#define BN    256
#define BK    32
#define NT    (DIM / BK)     // 64 K-steps
#define NCH   (VOCAB / BN)   // 256 vocab chunks
#define NTB   (N_TOK / BM)   // 16 token blocks
#define SLOT  8192           // shorts per 256x32 tile (16 KB)

__device__ __forceinline__ unsigned short f2bf(float x) {
    unsigned u = __float_as_uint(x);
    unsigned r = (u + 0x7fffu + ((u >> 16) & 1u)) >> 16;   // RNE
    return (unsigned short)r;
}

__device__ __forceinline__ void gload_lds16(const void* g, void* l) {
    __builtin_amdgcn_global_load_lds(
        (const __attribute__((address_space(1))) void*)g,
        (__attribute__((address_space(3))) void*)l, 16, 0, 0);
}

__device__ __forceinline__ void bar() {
    asm volatile("" ::: "memory");
    __builtin_amdgcn_s_barrier();
    asm volatile("" ::: "memory");
}

// ---------------------------------------------------------------- convert ---
__global__ __launch_bounds__(256) void convert_f32_bf16(
    const float* __restrict__ src, unsigned short* __restrict__ dst, long n)
{
    long i = ((long)blockIdx.x * 256 + threadIdx.x) * 8;
    if (i + 8 > n) return;
    f32x8 v = *(const f32x8*)(src + i);
    u16x8 o;
    #pragma unroll
    for (int j = 0; j < 8; ++j) o[j] = f2bf(v[j]);
    *(u16x8*)(dst + i) = o;
}

// -------------------------------------------- 256^2 BK=32 ring GEMM+LSE ----
__global__ __launch_bounds__(512, 4) void gemm_lse(
    const unsigned short* __restrict__ hA,    // [4096][2048] bf16 bits
    const unsigned short* __restrict__ Wb,    // [seg_rows][2048] bf16 bits
    float* __restrict__ part_m, float* __restrict__ part_s, int chunk0)
{
    __shared__ unsigned short A_lds[2][SLOT];   // 32 KB
    __shared__ unsigned short B_lds[2][SLOT];   // 32 KB

    const int tid  = threadIdx.x;
    const int lane = tid & 63;
    const int w    = tid >> 6;       // wave 0..7
    const int wm   = w >> 2;         // 0..1 : token half (128 rows)
    const int wn   = w & 3;          // 0..3 : vocab quarter (64 cols)

    // bijective XCD-aware remap (m204), token-fastest decode
    const int nwg  = gridDim.x;
    const int orig = blockIdx.x;
    const int q8 = nwg >> 3, r8 = nwg & 7;
    const int xcd = orig & 7;
    const int wg  = (xcd < r8 ? xcd * (q8 + 1) : r8 * (q8 + 1) + (xcd - r8) * q8)
                    + (orig >> 3);
    const int tok_blk = wg & (NTB - 1);
    const int voc_blk = wg >> 4;                 // NTB == 16

    const long arow0 = (long)tok_blk * BM;
    const long brow0 = (long)voc_blk * BM;
    const unsigned short* Ab = hA + arow0 * DIM;
    const unsigned short* Bb = Wb + brow0 * DIM;

    f32x16 acc[4][2];
    #pragma unroll
    for (int i = 0; i < 4; ++i)
        #pragma unroll
        for (int j = 0; j < 2; ++j)
            #pragma unroll
            for (int e = 0; e < 16; ++e)
                acc[i][j][e] = 0.f;

    // ---- staging invariants: per thread 2 chunks per operand per step ----
    // tile = 256 rows x 32 cols bf16 = 1024 x 16-B chunks; idx = j*512 + tid;
    // r = idx>>2, c = idx&3; source chunk pre-swizzled c ^ ((r>>1)&3) so the
    // linear gload_lds dest yields LDS[r][c] = G[r][c ^ ((r>>1)&3)].
    long soff[2];  int dbase[2];
    #pragma unroll
    for (int j = 0; j < 2; ++j) {
        const int idx = j * 512 + tid;
        const int r = idx >> 2, c = idx & 3;
        soff[j]  = (long)r * DIM + (c ^ ((r >> 1) & 3)) * 8;
        dbase[j] = (j * 512 + w * 64) * 8;
    }
#define STAGE_OP(G, LDSP)                                                     \
    _Pragma("unroll")                                                         \
    for (int j = 0; j < 2; ++j)                                               \
        gload_lds16((G) + soff[j], (LDSP) + dbase[j]);

    // prologue: tile 0 into buf 0
    STAGE_OP(Ab, &A_lds[0][0])
    STAGE_OP(Bb, &B_lds[0][0])
    asm volatile("s_waitcnt vmcnt(0)" ::: "memory");
    bar();

    // ---- read-side addressing (bytes) ----
    // A row = wm*128 + q*32 + (lane&31); B row = wn*64 + nf*32 + (lane&31);
    // row stride 64 B (4 chunks); G-chunk (2kk + lane>>5) read at LDS chunk
    // (2kk + lane>>5) ^ ((lane>>1)&3)  [row>>1 & 3 == lane>>1 & 3, since all
    // row bases are multiples of 32].
    const int h5   = lane >> 5;
    const int swzc = (lane >> 1) & 3;
    const int rowb = (lane & 31) * 64;
    const int ch0  = ((0 + h5) ^ swzc) * 16;   // kk = 0
    const int ch1  = ((2 + h5) ^ swzc) * 16;   // kk = 1

// One K-step. WAR safety with ONE barrier: reads of tile t complete before
// MFMA-t issues (lgkm), hence before bar(); stage(t+1) writes are issued this
// step but land under vmcnt(0) before bar(); step t+1 overwrites buf[t&1]
// only after that barrier.
#define KSTEP(CUR, NXT, t)                                                    \
    {                                                                         \
        if ((t) + 1 < NT) {                                                   \
            STAGE_OP(Ab + ((t) + 1) * BK, &A_lds[NXT][0])                     \
            STAGE_OP(Bb + ((t) + 1) * BK, &B_lds[NXT][0])                     \
        }                                                                     \
        const char* Ac = (const char*)&A_lds[CUR][0] + wm * 8192 + rowb;      \
        const char* Bc = (const char*)&B_lds[CUR][0] + wn * 4096 + rowb;      \
        bf16x8 a[4][2], b[2][2];                                              \
        _Pragma("unroll")                                                     \
        for (int q = 0; q < 4; ++q) {                                         \
            a[q][0] = *(const bf16x8*)(Ac + q * 2048 + ch0);                  \
            a[q][1] = *(const bf16x8*)(Ac + q * 2048 + ch1);                  \
        }                                                                     \
        _Pragma("unroll")                                                     \
        for (int nf = 0; nf < 2; ++nf) {                                      \
            b[nf][0] = *(const bf16x8*)(Bc + nf * 2048 + ch0);                \
            b[nf][1] = *(const bf16x8*)(Bc + nf * 2048 + ch1);                \
        }                                                                     \
        __builtin_amdgcn_s_setprio(1);                                        \
        _Pragma("unroll")                                                     \
        for (int kk = 0; kk < 2; ++kk)                                        \
            _Pragma("unroll")                                                 \
            for (int q = 0; q < 4; ++q)                                       \
                _Pragma("unroll")                                             \
                for (int nf = 0; nf < 2; ++nf)                                \
                    acc[q][nf] = __builtin_amdgcn_mfma_f32_32x32x16_bf16(     \
                        a[q][kk], b[nf][kk], acc[q][nf], 0, 0, 0);            \
        __builtin_amdgcn_s_setprio(0);                                        \
        asm volatile("s_waitcnt vmcnt(0)" ::: "memory");                      \
        bar();                                                                \
    }

    for (int t = 0; t < NT; t += 2) {
        KSTEP(0, 1, t)
        KSTEP(1, 0, t + 1)
    }
#undef KSTEP
#undef STAGE_OP

    // ---- epilogue: per-token (max, sumexp) over this block's 256 cols ----
    // red arrays overlaid on A_lds (loop fully drained by final bar()).
    float* red_m = (float*)&A_lds[0][0];          // 4 KB
    float* red_s = ((float*)&A_lds[0][0]) + 1024; // 4 KB
    // 32x32 C/D: col = lane&31, row = (reg&3) + 8*(reg>>2) + 4*(lane>>5).
    #pragma unroll
    for (int q = 0; q < 4; ++q) {
        #pragma unroll
        for (int rg = 0; rg < 16; ++rg) {
            float v0 = acc[q][0][rg], v1 = acc[q][1][rg];
            float mx = fmaxf(v0, v1);
            #pragma unroll
            for (int msk = 1; msk < 32; msk <<= 1)
                mx = fmaxf(mx, __shfl_xor(mx, msk, 64));
            float se = __expf(v0 - mx) + __expf(v1 - mx);
            #pragma unroll
            for (int msk = 1; msk < 32; msk <<= 1)
                se += __shfl_xor(se, msk, 64);
            if ((lane & 31) == 0) {
                const int row = wm * 128 + q * 32 + (rg & 3) + 8 * (rg >> 2) +
                                4 * (lane >> 5);
                red_m[row * 4 + wn] = mx;
                red_s[row * 4 + wn] = se;
            }
        }
    }
    __syncthreads();
    if (tid < 256) {
        float M = red_m[tid * 4], S = red_s[tid * 4];
        #pragma unroll
        for (int j = 1; j < 4; ++j) {
            const float m2 = red_m[tid * 4 + j], s2 = red_s[tid * 4 + j];
            const float Mn = fmaxf(M, m2);
            S = S * __expf(M - Mn) + s2 * __expf(m2 - Mn);
            M = Mn;
        }
        part_m[(arow0 + tid) * NCH + chunk0 + voc_blk] = M;
        part_s[(arow0 + tid) * NCH + chunk0 + voc_blk] = S;
    }
}

// ------------------------------------------------------- exact label dot ----
__global__ __launch_bounds__(256) void label_dot(
    const float* __restrict__ h, const float* __restrict__ W,
    const void* __restrict__ labels, float* __restrict__ lab_logit)
{
    bool is64 = true;
    #pragma unroll
    for (int i = 0; i < 8; ++i) {
        long long v = ((const long long*)labels)[i];
        if (v < 0 || v >= VOCAB) is64 = false;
    }
    const int t = blockIdx.x;
    const int lab = is64 ? (int)((const long long*)labels)[t]
                         : ((const int*)labels)[t];
    const float4* hp = (const float4*)(h + (long)t * DIM);
    const float4* wp = (const float4*)(W + (long)lab * DIM);
    float s = 0.f;
    #pragma unroll
    for (int j = 0; j < 2; ++j) {
        const float4 a = hp[threadIdx.x + j * 256];
        const float4 b = wp[threadIdx.x + j * 256];
        s += a.x * b.x + a.y * b.y + a.z * b.z + a.w * b.w;
    }
    #pragma unroll
    for (int msk = 1; msk < 64; msk <<= 1) s += __shfl_xor(s, msk, 64);
    __shared__ float ps[4];
    if ((threadIdx.x & 63) == 0) ps[threadIdx.x >> 6] = s;
    __syncthreads();
    if (threadIdx.x == 0) lab_logit[t] = ps[0] + ps[1] + ps[2] + ps[3];
}

// ---------------------------------------------------- per-token LSE merge ---
__global__ __launch_bounds__(256) void finalize_nll(
    const float* __restrict__ part_m, const float* __restrict__ part_s,
    const float* __restrict__ lab_logit, const float* __restrict__ wts,
    float* __restrict__ wnll)
{
    const int t    = blockIdx.x * 4 + (threadIdx.x >> 6);  // one wave / token
    const int lane = threadIdx.x & 63;
    float m = -3.4e38f, s = 0.f;
    #pragma unroll
    for (int j = 0; j < 4; ++j) {
        const int c = j * 64 + lane;
        const float pm = part_m[(long)t * NCH + c];
        const float ps = part_s[(long)t * NCH + c];
        const float M = fmaxf(m, pm);
        s = s * __expf(m - M) + ps * __expf(pm - M);
        m = M;
    }
    #pragma unroll
    for (int msk = 1; msk < 64; msk <<= 1) {
        const float om = __shfl_xor(m, msk, 64);
        const float os = __shfl_xor(s, msk, 64);
        const float M = fmaxf(m, om);
        s = s * __expf(m - M) + os * __expf(om - M);
        m = M;
    }
    if (lane == 0) {
        const float lse = m + logf(s);
        wnll[t] = wts[t] * (lse - lab_logit[t]);
    }
}

// -------------------------------------------------- deterministic reduce ----
__global__ __launch_bounds__(1024) void final_reduce(
    const float* __restrict__ wnll, const float* __restrict__ wts,
    float* __restrict__ out)
{
    float a = 0.f, b = 0.f;
    #pragma unroll
    for (int j = 0; j < 4; ++j) {
        const int i = threadIdx.x + j * 1024;
        a += wnll[i];
        b += wts[i];
    }
    #pragma unroll
    for (int msk = 1; msk < 64; msk <<= 1) {
        a += __shfl_xor(a, msk, 64);
        b += __shfl_xor(b, msk, 64);
    }
    __shared__ float pa[16], pb[16];
    if ((threadIdx.x & 63) == 0) {
        pa[threadIdx.x >> 6] = a;
        pb[threadIdx.x >> 6] = b;
    }
    __syncthreads();
    if (threadIdx.x == 0) {
        float A = 0.f, B = 0.f;
        #pragma unroll
        for (int i = 0; i < 16; ++i) { A += pa[i]; B += pb[i]; }
        out[0] = A / B;
    }
}

// ----------------------------------------------------------------- launch ---
extern "C" void kernel_launch(void* const* d_in, const int* in_sizes, int n_in,
                              void* d_out, int out_size, void* d_ws, size_t ws_size,
                              hipStream_t stream)
{
    const float* h      = (const float*)d_in[0];
    const void*  labels = d_in[1];
    const float* wts    = (const float*)d_in[2];
    const float* W      = (const float*)d_in[3];
    float* out = (float*)d_out;

    char* ws = (char*)d_ws;
    unsigned short* h_bf      = (unsigned short*)(ws);                 // 16 MB
    float*          part_m    = (float*)(ws + (16u << 20));            //  4 MB
    float*          part_s    = (float*)(ws + (24u << 20));            //  4 MB
    float*          lab_logit = (float*)(ws + (32u << 20));            // 16 KB
    float*          wnll      = (float*)(ws + (32u << 20) + 16384);    // 16 KB
    unsigned short* wseg      = (unsigned short*)(ws + (32u << 20) + 32768);
    const size_t base = (size_t)(32u << 20) + 32768;

    long segmax = 0;
    if (ws_size > base) segmax = (long)((ws_size - base) / ((size_t)DIM * 2));
    segmax &= ~255L;
    if (segmax > VOCAB) segmax = VOCAB;
    if (segmax < 256)   segmax = 256;   // require ws_size >= ~34 MB

    // 0) h -> bf16
    convert_f32_bf16<<<(N_TOK * DIM) / (256 * 8), 256, 0, stream>>>(
        h, h_bf, (long)N_TOK * DIM);

    // 1) segmented W conversion + fused GEMM/LSE partials
    for (long v0 = 0; v0 < VOCAB; v0 += segmax) {
        const long rows = (VOCAB - v0) < segmax ? (VOCAB - v0) : segmax;
        convert_f32_bf16<<<(int)(rows * DIM / (256 * 8)), 256, 0, stream>>>(
            W + v0 * DIM, wseg, rows * (long)DIM);
        const int nwg = (int)(rows / BM) * NTB;
        gemm_lse<<<nwg, 512, 0, stream>>>(h_bf, wseg, part_m, part_s,
                                          (int)(v0 / BN));
    }

    // 2) exact label logits (fp32)
    label_dot<<<N_TOK, 256, 0, stream>>>(h, W, labels, lab_logit);

    // 3) per-token LSE merge -> w*nll
    finalize_nll<<<N_TOK / 4, 256, 0, stream>>>(part_m, part_s, lab_logit,
                                                wts, wnll);

    // 4) weighted mean
    final_reduce<<<1, 1024, 0, stream>>>(wnll, wts, out);
}

// Round 7
// 2085.626 us; speedup vs baseline: 12.3235x; 12.3235x over previous
//
#include <hip/hip_runtime.h>

// ---------------------------------------------------------------------------
// FusedSparseLMHead: weighted-mean CE over h @ W^T without materializing logits.
//   h: [4096, 2048] f32, W: [65536, 2048] f32, labels: [4096] int, w: [4096] f32
// Round 7: 256x256, BK=64, 32x32x16 MFMA, double-buffered A/B (128 KB LDS),
//   ONE barrier + ONE vmcnt(0) per K-step; all 24 ds_read_b128 batched up
//   front (single lgkm exposure), 32-MFMA setprio burst; stage(t+1) issued at
//   top of step t (full-K-step slack >> L2 latency). launch_bounds(512,2)
//   (r6's (512,4) forced 128-reg cap -> acc spill -> 84 GB scratch writes).
//   Epilogue: 16-wide shfl masks only (r5's 32-wide shfls caused the 1.0e8
//   bank-conflict count), 8-partial online-LSE merge.
// ---------------------------------------------------------------------------

typedef __attribute__((ext_vector_type(8)))  short bf16x8;
typedef __attribute__((ext_vector_type(16))) float f32x16;
typedef __attribute__((ext_vector_type(8)))  float f32x8;
typedef __attribute__((ext_vector_type(8)))  unsigned short u16x8;

#define N_TOK 4096
#define DIM   2048
#define VOCAB 65536
#define BM    256
#define BN    256
#define BK    64
#define NT    (DIM / BK)     // 32 K-steps
#define NCH   (VOCAB / BN)   // 256 vocab chunks
#define NTB   (N_TOK / BM)   // 16 token blocks
#define TSLOT (BM * BK)      // 16384 shorts per 256x64 tile (32 KB)

__device__ __forceinline__ unsigned short f2bf(float x) {
    unsigned u = __float_as_uint(x);
    unsigned r = (u + 0x7fffu + ((u >> 16) & 1u)) >> 16;   // RNE
    return (unsigned short)r;
}

__device__ __forceinline__ void gload_lds16(const void* g, void* l) {
    __builtin_amdgcn_global_load_lds(
        (const __attribute__((address_space(1))) void*)g,
        (__attribute__((address_space(3))) void*)l, 16, 0, 0);
}

__device__ __forceinline__ void bar() {
    asm volatile("" ::: "memory");
    __builtin_amdgcn_s_barrier();
    asm volatile("" ::: "memory");
}

// ---------------------------------------------------------------- convert ---
__global__ __launch_bounds__(256) void convert_f32_bf16(
    const float* __restrict__ src, unsigned short* __restrict__ dst, long n)
{
    long i = ((long)blockIdx.x * 256 + threadIdx.x) * 8;
    if (i + 8 > n) return;
    f32x8 v = *(const f32x8*)(src + i);
    u16x8 o;
    #pragma unroll
    for (int j = 0; j < 8; ++j) o[j] = f2bf(v[j]);
    *(u16x8*)(dst + i) = o;
}

// -------------------------------------- 256^2 BK=64 1-barrier GEMM+LSE -----
__global__ __launch_bounds__(512, 2) void gemm_lse(
    const unsigned short* __restrict__ hA,    // [4096][2048] bf16 bits
    const unsigned short* __restrict__ Wb,    // [seg_rows][2048] bf16 bits
    float* __restrict__ part_m, float* __restrict__ part_s, int chunk0)
{
    __shared__ unsigned short A_lds[2][TSLOT];   // 64 KB
    __shared__ unsigned short B_lds[2][TSLOT];   // 64 KB

    const int tid  = threadIdx.x;
    const int lane = tid & 63;
    const int w    = tid >> 6;       // wave 0..7
    const int wm   = w >> 2;         // 0..1 : token half (128 rows)
    const int wn   = w & 3;          // 0..3 : vocab quarter (64 cols)

    // bijective XCD-aware remap (m204), token-fastest decode
    const int nwg  = gridDim.x;
    const int orig = blockIdx.x;
    const int q8 = nwg >> 3, r8 = nwg & 7;
    const int xcd = orig & 7;
    const int wg  = (xcd < r8 ? xcd * (q8 + 1) : r8 * (q8 + 1) + (xcd - r8) * q8)
                    + (orig >> 3);
    const int tok_blk = wg & (NTB - 1);
    const int voc_blk = wg >> 4;                 // NTB == 16

    const long arow0 = (long)tok_blk * BM;
    const long brow0 = (long)voc_blk * BM;
    const unsigned short* Ab = hA + arow0 * DIM;
    const unsigned short* Bb = Wb + brow0 * DIM;

    f32x16 acc[4][2];
    #pragma unroll
    for (int i = 0; i < 4; ++i)
        #pragma unroll
        for (int j = 0; j < 2; ++j)
            #pragma unroll
            for (int e = 0; e < 16; ++e)
                acc[i][j][e] = 0.f;

    // ---- staging: 256 rows x 64 cols bf16 = 2048 x 16-B chunks; 4/thread.
    // idx = j*512 + tid; r = idx>>3, c = idx&7; source chunk (c ^ (r&7)) so
    // the linear gload_lds dest yields LDS[r][c] = G[r][c ^ (r&7)] (rule 21).
    long soff[4];  int dbase[4];
    #pragma unroll
    for (int j = 0; j < 4; ++j) {
        const int idx = j * 512 + tid;
        const int r = idx >> 3, c = idx & 7;
        soff[j]  = (long)r * DIM + (c ^ (r & 7)) * 8;
        dbase[j] = (j * 512 + w * 64) * 8;
    }
#define STAGE_OP(G, LDSP)                                                     \
    _Pragma("unroll")                                                         \
    for (int j = 0; j < 4; ++j)                                               \
        gload_lds16((G) + soff[j], (LDSP) + dbase[j]);

    // prologue: tile 0 into buf 0
    STAGE_OP(Ab, &A_lds[0][0])
    STAGE_OP(Bb, &B_lds[0][0])
    asm volatile("s_waitcnt vmcnt(0)" ::: "memory");
    bar();

    // ---- read addressing (bytes): row*128 + ((kk*32 + hi16) ^ swz).
    // A row = wm*128 + q*32 + (lane&31); B row = wn*64 + nf*32 + (lane&31);
    // row&7 == lane&7 (bases are multiples of 32) -> read XOR = (lane&7)<<4.
    // mod-128 bank check: row term vanishes; 8-lane groups cover all 32 banks.
    const int swz  = (lane & 7) << 4;
    const int hi16 = (lane >> 5) << 4;
    const int rowb = (lane & 31) * 128;

// One K-step, ONE barrier. WAR safety: each wave's MFMAs force its ds_reads
// complete (lgkm) before it reaches bar(); stage(t+1) overwrites buf[NXT]
// (not CUR); t+1's overwrite of buf[CUR]... never: parity alternates. The
// vmcnt(0) at step end has a full K-step of slack since issue at step top.
#define KSTEP(CUR, NXT, t)                                                    \
    {                                                                         \
        if ((t) + 1 < NT) {                                                   \
            STAGE_OP(Ab + ((t) + 1) * BK, &A_lds[NXT][0])                     \
            STAGE_OP(Bb + ((t) + 1) * BK, &B_lds[NXT][0])                     \
        }                                                                     \
        const char* Ac = (const char*)&A_lds[CUR][0] + wm * 16384 + rowb;     \
        const char* Bc = (const char*)&B_lds[CUR][0] + wn * 8192 + rowb;      \
        bf16x8 b[2][4], a[4][4];                                              \
        _Pragma("unroll")                                                     \
        for (int nf = 0; nf < 2; ++nf)                                        \
            _Pragma("unroll")                                                 \
            for (int kk = 0; kk < 4; ++kk)                                    \
                b[nf][kk] = *(const bf16x8*)(Bc + nf * 4096 +                 \
                                             ((kk * 32 + hi16) ^ swz));       \
        _Pragma("unroll")                                                     \
        for (int q = 0; q < 4; ++q)                                           \
            _Pragma("unroll")                                                 \
            for (int kk = 0; kk < 4; ++kk)                                    \
                a[q][kk] = *(const bf16x8*)(Ac + q * 4096 +                   \
                                            ((kk * 32 + hi16) ^ swz));        \
        __builtin_amdgcn_s_setprio(1);                                        \
        _Pragma("unroll")                                                     \
        for (int kk = 0; kk < 4; ++kk)                                        \
            _Pragma("unroll")                                                 \
            for (int q = 0; q < 4; ++q)                                       \
                _Pragma("unroll")                                             \
                for (int nf = 0; nf < 2; ++nf)                                \
                    acc[q][nf] = __builtin_amdgcn_mfma_f32_32x32x16_bf16(     \
                        a[q][kk], b[nf][kk], acc[q][nf], 0, 0, 0);            \
        __builtin_amdgcn_s_setprio(0);                                        \
        asm volatile("s_waitcnt vmcnt(0)" ::: "memory");                      \
        bar();                                                                \
    }

    for (int t = 0; t < NT; t += 2) {
        KSTEP(0, 1, t)
        KSTEP(1, 0, t + 1)
    }
#undef KSTEP
#undef STAGE_OP

    // ---- epilogue: per-token (max, sumexp) over this block's 256 cols ----
    // Masks 1..8 only (16-wide groups; 32-wide shfl caused 1e8 conflicts).
    // Each 16-lane group -> one (row, col-half) partial; merge 8 per token.
    float* red_m = (float*)&A_lds[0][0];          //  8 KB
    float* red_s = ((float*)&A_lds[0][0]) + 2048; //  8 KB
    // 32x32 C/D: col = lane&31, row = (reg&3) + 8*(reg>>2) + 4*(lane>>5).
    #pragma unroll
    for (int q = 0; q < 4; ++q) {
        #pragma unroll
        for (int rg = 0; rg < 16; ++rg) {
            float v0 = acc[q][0][rg], v1 = acc[q][1][rg];
            float mx = fmaxf(v0, v1);
            #pragma unroll
            for (int msk = 1; msk < 16; msk <<= 1)
                mx = fmaxf(mx, __shfl_xor(mx, msk, 64));
            float se = __expf(v0 - mx) + __expf(v1 - mx);
            #pragma unroll
            for (int msk = 1; msk < 16; msk <<= 1)
                se += __shfl_xor(se, msk, 64);
            if ((lane & 15) == 0) {
                const int row = wm * 128 + q * 32 + (rg & 3) + 8 * (rg >> 2) +
                                4 * (lane >> 5);
                const int s8 = wn * 2 + ((lane >> 4) & 1);
                red_m[row * 8 + s8] = mx;
                red_s[row * 8 + s8] = se;
            }
        }
    }
    __syncthreads();
    if (tid < 256) {
        float M = red_m[tid * 8], S = red_s[tid * 8];
        #pragma unroll
        for (int j = 1; j < 8; ++j) {
            const float m2 = red_m[tid * 8 + j], s2 = red_s[tid * 8 + j];
            const float Mn = fmaxf(M, m2);
            S = S * __expf(M - Mn) + s2 * __expf(m2 - Mn);
            M = Mn;
        }
        part_m[(arow0 + tid) * NCH + chunk0 + voc_blk] = M;
        part_s[(arow0 + tid) * NCH + chunk0 + voc_blk] = S;
    }
}

// ------------------------------------------------------- exact label dot ----
__global__ __launch_bounds__(256) void label_dot(
    const float* __restrict__ h, const float* __restrict__ W,
    const void* __restrict__ labels, float* __restrict__ lab_logit)
{
    bool is64 = true;
    #pragma unroll
    for (int i = 0; i < 8; ++i) {
        long long v = ((const long long*)labels)[i];
        if (v < 0 || v >= VOCAB) is64 = false;
    }
    const int t = blockIdx.x;
    const int lab = is64 ? (int)((const long long*)labels)[t]
                         : ((const int*)labels)[t];
    const float4* hp = (const float4*)(h + (long)t * DIM);
    const float4* wp = (const float4*)(W + (long)lab * DIM);
    float s = 0.f;
    #pragma unroll
    for (int j = 0; j < 2; ++j) {
        const float4 a = hp[threadIdx.x + j * 256];
        const float4 b = wp[threadIdx.x + j * 256];
        s += a.x * b.x + a.y * b.y + a.z * b.z + a.w * b.w;
    }
    #pragma unroll
    for (int msk = 1; msk < 64; msk <<= 1) s += __shfl_xor(s, msk, 64);
    __shared__ float ps[4];
    if ((threadIdx.x & 63) == 0) ps[threadIdx.x >> 6] = s;
    __syncthreads();
    if (threadIdx.x == 0) lab_logit[t] = ps[0] + ps[1] + ps[2] + ps[3];
}

// ---------------------------------------------------- per-token LSE merge ---
__global__ __launch_bounds__(256) void finalize_nll(
    const float* __restrict__ part_m, const float* __restrict__ part_s,
    const float* __restrict__ lab_logit, const float* __restrict__ wts,
    float* __restrict__ wnll)
{
    const int t    = blockIdx.x * 4 + (threadIdx.x >> 6);  // one wave / token
    const int lane = threadIdx.x & 63;
    float m = -3.4e38f, s = 0.f;
    #pragma unroll
    for (int j = 0; j < 4; ++j) {
        const int c = j * 64 + lane;
        const float pm = part_m[(long)t * NCH + c];
        const float ps = part_s[(long)t * NCH + c];
        const float M = fmaxf(m, pm);
        s = s * __expf(m - M) + ps * __expf(pm - M);
        m = M;
    }
    #pragma unroll
    for (int msk = 1; msk < 64; msk <<= 1) {
        const float om = __shfl_xor(m, msk, 64);
        const float os = __shfl_xor(s, msk, 64);
        const float M = fmaxf(m, om);
        s = s * __expf(m - M) + os * __expf(om - M);
        m = M;
    }
    if (lane == 0) {
        const float lse = m + logf(s);
        wnll[t] = wts[t] * (lse - lab_logit[t]);
    }
}

// -------------------------------------------------- deterministic reduce ----
__global__ __launch_bounds__(1024) void final_reduce(
    const float* __restrict__ wnll, const float* __restrict__ wts,
    float* __restrict__ out)
{
    float a = 0.f, b = 0.f;
    #pragma unroll
    for (int j = 0; j < 4; ++j) {
        const int i = threadIdx.x + j * 1024;
        a += wnll[i];
        b += wts[i];
    }
    #pragma unroll
    for (int msk = 1; msk < 64; msk <<= 1) {
        a += __shfl_xor(a, msk, 64);
        b += __shfl_xor(b, msk, 64);
    }
    __shared__ float pa[16], pb[16];
    if ((threadIdx.x & 63) == 0) {
        pa[threadIdx.x >> 6] = a;
        pb[threadIdx.x >> 6] = b;
    }
    __syncthreads();
    if (threadIdx.x == 0) {
        float A = 0.f, B = 0.f;
        #pragma unroll
        for (int i = 0; i < 16; ++i) { A += pa[i]; B += pb[i]; }
        out[0] = A / B;
    }
}

// ----------------------------------------------------------------- launch ---
extern "C" void kernel_launch(void* const* d_in, const int* in_sizes, int n_in,
                              void* d_out, int out_size, void* d_ws, size_t ws_size,
                              hipStream_t stream)
{
    const float* h      = (const float*)d_in[0];
    const void*  labels = d_in[1];
    const float* wts    = (const float*)d_in[2];
    const float* W      = (const float*)d_in[3];
    float* out = (float*)d_out;

    char* ws = (char*)d_ws;
    unsigned short* h_bf      = (unsigned short*)(ws);                 // 16 MB
    float*          part_m    = (float*)(ws + (16u << 20));            //  4 MB
    float*          part_s    = (float*)(ws + (24u << 20));            //  4 MB
    float*          lab_logit = (float*)(ws + (32u << 20));            // 16 KB
    float*          wnll      = (float*)(ws + (32u << 20) + 16384);    // 16 KB
    unsigned short* wseg      = (unsigned short*)(ws + (32u << 20) + 32768);
    const size_t base = (size_t)(32u << 20) + 32768;

    long segmax = 0;
    if (ws_size > base) segmax = (long)((ws_size - base) / ((size_t)DIM * 2));
    segmax &= ~255L;
    if (segmax > VOCAB) segmax = VOCAB;
    if (segmax < 256)   segmax = 256;   // require ws_size >= ~34 MB

    // 0) h -> bf16
    convert_f32_bf16<<<(N_TOK * DIM) / (256 * 8), 256, 0, stream>>>(
        h, h_bf, (long)N_TOK * DIM);

    // 1) segmented W conversion + fused GEMM/LSE partials
    for (long v0 = 0; v0 < VOCAB; v0 += segmax) {
        const long rows = (VOCAB - v0) < segmax ? (VOCAB - v0) : segmax;
        convert_f32_bf16<<<(int)(rows * DIM / (256 * 8)), 256, 0, stream>>>(
            W + v0 * DIM, wseg, rows * (long)DIM);
        const int nwg = (int)(rows / BM) * NTB;
        gemm_lse<<<nwg, 512, 0, stream>>>(h_bf, wseg, part_m, part_s,
                                          (int)(v0 / BN));
    }

    // 2) exact label logits (fp32)
    label_dot<<<N_TOK, 256, 0, stream>>>(h, W, labels, lab_logit);

    // 3) per-token LSE merge -> w*nll
    finalize_nll<<<N_TOK / 4, 256, 0, stream>>>(part_m, part_s, lab_logit,
                                                wts, wnll);

    // 4) weighted mean
    final_reduce<<<1, 1024, 0, stream>>>(wnll, wts, out);
}

// Round 8
// 1641.839 us; speedup vs baseline: 15.6546x; 1.2703x over previous
//
#include <hip/hip_runtime.h>

// ---------------------------------------------------------------------------
// FusedSparseLMHead: weighted-mean CE over h @ W^T without materializing logits.
//   h: [4096, 2048] f32, W: [65536, 2048] f32, labels: [4096] int, w: [4096] f32
// Round 8: SINGLE-LAUNCH fused-convert GEMM+LSE.
//   - 4096 blocks (16 token x 256 vocab chunks), W read fp32 directly,
//     converted in-kernel (reg-stage: 8 float4 -> cvt -> 4 swizzled ds_write).
//   - 16x16x32 MFMA with r4's PROVEN 0-conflict LDS addressing (16-row reads;
//     r5-r7's 32-row pattern is a structural 4-way conflict = 1.0e8 counts).
//   - 4 phases/K-step: {ds_reads + 1 stage action; bar; setprio + 16 MFMA}.
//     One vmcnt(0)+lgkmcnt(0) before the ph3 barrier (A-gloads get 3 phases
//     of slack; B reg-loads are compiler-tracked) = publication point.
// ---------------------------------------------------------------------------

typedef __attribute__((ext_vector_type(8)))  short bf16x8;
typedef __attribute__((ext_vector_type(4)))  float f32x4;
typedef __attribute__((ext_vector_type(8)))  float f32x8;
typedef __attribute__((ext_vector_type(8)))  unsigned short u16x8;

#define N_TOK 4096
#define DIM   2048
#define VOCAB 65536
#define BM    256
#define BN    256
#define BK    64
#define NT    (DIM / BK)     // 32 K-steps
#define NCH   (VOCAB / BN)   // 256 vocab chunks
#define NTB   (N_TOK / BM)   // 16 token blocks
#define TSLOT (BM * BK)      // 16384 shorts per 256x64 tile (32 KB)

__device__ __forceinline__ unsigned short f2bf(float x) {
    unsigned u = __float_as_uint(x);
    unsigned r = (u + 0x7fffu + ((u >> 16) & 1u)) >> 16;   // RNE
    return (unsigned short)r;
}

__device__ __forceinline__ void gload_lds16(const void* g, void* l) {
    __builtin_amdgcn_global_load_lds(
        (const __attribute__((address_space(1))) void*)g,
        (__attribute__((address_space(3))) void*)l, 16, 0, 0);
}

__device__ __forceinline__ void bar() {
    asm volatile("" ::: "memory");
    __builtin_amdgcn_s_barrier();
    asm volatile("" ::: "memory");
}

// ---------------------------------------------------------------- convert ---
__global__ __launch_bounds__(256) void convert_f32_bf16(
    const float* __restrict__ src, unsigned short* __restrict__ dst, long n)
{
    long i = ((long)blockIdx.x * 256 + threadIdx.x) * 8;
    if (i + 8 > n) return;
    f32x8 v = *(const f32x8*)(src + i);
    u16x8 o;
    #pragma unroll
    for (int j = 0; j < 8; ++j) o[j] = f2bf(v[j]);
    *(u16x8*)(dst + i) = o;
}

// --------------------------- single-launch fused-convert 256^2 GEMM+LSE ----
__global__ __launch_bounds__(512, 2) void gemm_lse(
    const unsigned short* __restrict__ hA,    // [4096][2048] bf16 bits
    const float* __restrict__ Wf,             // [65536][2048] fp32
    float* __restrict__ part_m, float* __restrict__ part_s)
{
    __shared__ unsigned short A_lds[2][TSLOT];   // 64 KB
    __shared__ unsigned short B_lds[2][TSLOT];   // 64 KB

    const int tid  = threadIdx.x;
    const int lane = tid & 63;
    const int w    = tid >> 6;       // wave 0..7
    const int wm   = w >> 2;         // 0..1 : token half (128 rows)
    const int wn   = w & 3;          // 0..3 : vocab quarter (64 cols)

    // bijective XCD remap: nwg = 4096 (mult of 8) -> wg = xcd*512 + orig/8.
    // token-fastest decode => the 16 sharers of a B-panel are consecutive wg
    // on the SAME XCD -> B fp32 read from HBM once, L2-hit for the rest.
    const int orig = blockIdx.x;
    const int wg   = (orig & 7) * 512 + (orig >> 3);
    const int tok_blk = wg & (NTB - 1);
    const int voc_blk = wg >> 4;

    const long arow0 = (long)tok_blk * BM;
    const long brow0 = (long)voc_blk * BN;
    const unsigned short* Ab = hA + arow0 * DIM;
    const float* Wb = Wf + brow0 * DIM;

    f32x4 acc[8][4];
    #pragma unroll
    for (int i = 0; i < 8; ++i)
        #pragma unroll
        for (int j = 0; j < 4; ++j)
            acc[i][j] = (f32x4){0.f, 0.f, 0.f, 0.f};

    // ---- staging maps (A via gload_lds, B via reg-cvt-ds_write) ----------
    // chunk idx = j*512 + tid; r = idx>>3 (row), c = idx&7 (LDS chunk).
    // Layout (both operands): LDS[r][c] = G[r][c ^ (r&7)]  (16-B chunks).
    // gc = c ^ (r&7) = (tid&7) ^ ((tid>>3)&7)   [j*64 == 0 mod 8].
    const int rr0 = tid >> 3;                    // row for j=0 (64 rows per j)
    const int gc  = (tid & 7) ^ (rr0 & 7);       // source chunk (all j)
    const long aoff0 = (long)rr0 * DIM + gc * 8; // + j*64*DIM per j
    const int  adst0 = (w * 64) * 16;            // byte; + j*512*16 per j (wave-uniform)
    const int  boff0 = rr0 * DIM + gc * 8;       // fp32 elem; + j*64*DIM per j
    const int  bdst0 = (rr0 * 8 + (tid & 7)) * 8;// short; + j*4096 per j

#define STAGE_A(NXT, t)                                                       \
    _Pragma("unroll")                                                         \
    for (int j = 0; j < 4; ++j)                                               \
        gload_lds16(Ab + (t) * BK + aoff0 + (long)j * 64 * DIM,               \
                    (char*)&A_lds[NXT][0] + adst0 + j * 8192);

#define BLOAD(t)                                                              \
    _Pragma("unroll")                                                         \
    for (int j = 0; j < 4; ++j) {                                             \
        const float4* p = (const float4*)(Wb + (t) * BK + boff0 +             \
                                          (long)j * 64 * DIM);                \
        breg[2 * j]     = p[0];                                               \
        breg[2 * j + 1] = p[1];                                               \
    }

#define BCVT_WRITE(NXT, HALF)                                                 \
    _Pragma("unroll")                                                         \
    for (int j = 2 * (HALF); j < 2 * (HALF) + 2; ++j) {                       \
        u16x8 o;                                                              \
        o[0] = f2bf(breg[2 * j].x);     o[1] = f2bf(breg[2 * j].y);           \
        o[2] = f2bf(breg[2 * j].z);     o[3] = f2bf(breg[2 * j].w);           \
        o[4] = f2bf(breg[2 * j + 1].x); o[5] = f2bf(breg[2 * j + 1].y);       \
        o[6] = f2bf(breg[2 * j + 1].z); o[7] = f2bf(breg[2 * j + 1].w);       \
        *(u16x8*)(&B_lds[NXT][bdst0 + j * 4096]) = o;                         \
    }

    // ---- read-side addressing (r4's proven 0-conflict pattern) -----------
    const int swz   = (lane & 7) << 4;
    const int colb0 = (lane >> 4) * 16;
    const int lrow  = lane & 15;

#define LDA(DST, Q, CUR)                                                      \
    _Pragma("unroll")                                                         \
    for (int f = 0; f < 2; ++f)                                               \
        _Pragma("unroll")                                                     \
        for (int kk = 0; kk < 2; ++kk)                                        \
            DST[f][kk] = *(const bf16x8*)((const char*)&A_lds[CUR][0] +       \
                (wm * 128 + (Q) * 32 + f * 16 + lrow) * 128 +                 \
                ((kk * 64 + colb0) ^ swz));

#define LDB(CUR)                                                              \
    _Pragma("unroll")                                                         \
    for (int nf = 0; nf < 4; ++nf)                                            \
        _Pragma("unroll")                                                     \
        for (int kk = 0; kk < 2; ++kk)                                        \
            bfr[nf][kk] = *(const bf16x8*)((const char*)&B_lds[CUR][0] +      \
                (wn * 64 + nf * 16 + lrow) * 128 +                            \
                ((kk * 64 + colb0) ^ swz));

#define MFMA_CLUST(AF, Q)                                                     \
    __builtin_amdgcn_s_setprio(1);                                            \
    _Pragma("unroll")                                                         \
    for (int kk = 0; kk < 2; ++kk)                                            \
        _Pragma("unroll")                                                     \
        for (int f = 0; f < 2; ++f)                                           \
            _Pragma("unroll")                                                 \
            for (int nf = 0; nf < 4; ++nf)                                    \
                acc[(Q) * 2 + f][nf] = __builtin_amdgcn_mfma_f32_16x16x32_bf16(\
                    AF[f][kk], bfr[nf][kk], acc[(Q) * 2 + f][nf], 0, 0, 0);   \
    __builtin_amdgcn_s_setprio(0);

    float4 breg[8];

    // prologue: tile 0 into buf 0
    STAGE_A(0, 0)
    BLOAD(0)
    BCVT_WRITE(0, 0)
    BCVT_WRITE(0, 1)
    asm volatile("s_waitcnt vmcnt(0) lgkmcnt(0)" ::: "memory");
    bar();

// One K-step, 4 phases. Publication point = ph3 barrier (all waits precede
// it); MFMA-q3 runs past it, overlapping step t+1's phase-0 reads.
#define KSTEP(CUR, NXT, t)                                                    \
    {                                                                         \
        bf16x8 afA[2][2], afB[2][2], bfr[4][2];                               \
        /* ph0: LDA q0 + LDB (12 ds_reads) | issue 4 A-gloads(t+1) */         \
        LDA(afA, 0, CUR)                                                      \
        LDB(CUR)                                                              \
        if ((t) + 1 < NT) { STAGE_A(NXT, (t) + 1) }                           \
        bar();                                                                \
        MFMA_CLUST(afA, 0)                                                    \
        /* ph1: LDA q1 | issue 8 B fp32 loads(t+1) */                         \
        LDA(afB, 1, CUR)                                                      \
        if ((t) + 1 < NT) { BLOAD((t) + 1) }                                  \
        bar();                                                                \
        MFMA_CLUST(afB, 1)                                                    \
        /* ph2: LDA q2 | cvt+write B half 0 (compiler waits breg) */          \
        LDA(afA, 2, CUR)                                                      \
        if ((t) + 1 < NT) { BCVT_WRITE(NXT, 0) }                              \
        bar();                                                                \
        MFMA_CLUST(afA, 2)                                                    \
        /* ph3: LDA q3 | cvt+write B half 1 | drain | publish */              \
        LDA(afB, 3, CUR)                                                      \
        if ((t) + 1 < NT) { BCVT_WRITE(NXT, 1) }                              \
        asm volatile("s_waitcnt vmcnt(0) lgkmcnt(0)" ::: "memory");           \
        bar();                                                                \
        MFMA_CLUST(afB, 3)                                                    \
    }

    for (int t = 0; t < NT; t += 2) {
        KSTEP(0, 1, t)
        KSTEP(1, 0, t + 1)
    }
#undef KSTEP
#undef LDA
#undef LDB
#undef MFMA_CLUST
#undef STAGE_A
#undef BLOAD
#undef BCVT_WRITE

    // ---- epilogue: per-token (max, sumexp) over this block's 256 cols ----
    // C frag layout (r4-verified): row = wm*128 + mf*16 + (lane>>4)*4 + r,
    // col = wn*64 + nf*16 + (lane&15).
    __syncthreads();   // all LDS reads done; safe to overlay red arrays
    float* red_m = (float*)&A_lds[0][0];          // 4 KB
    float* red_s = ((float*)&A_lds[0][0]) + 1024; // 4 KB
    #pragma unroll
    for (int mf = 0; mf < 8; ++mf) {
        #pragma unroll
        for (int r = 0; r < 4; ++r) {
            float v0 = acc[mf][0][r], v1 = acc[mf][1][r];
            float v2 = acc[mf][2][r], v3 = acc[mf][3][r];
            float mx = fmaxf(fmaxf(v0, v1), fmaxf(v2, v3));
            #pragma unroll
            for (int msk = 1; msk < 16; msk <<= 1)
                mx = fmaxf(mx, __shfl_xor(mx, msk, 64));
            float se = __expf(v0 - mx) + __expf(v1 - mx) +
                       __expf(v2 - mx) + __expf(v3 - mx);
            #pragma unroll
            for (int msk = 1; msk < 16; msk <<= 1)
                se += __shfl_xor(se, msk, 64);
            if ((lane & 15) == 0) {
                const int row = wm * 128 + mf * 16 + (lane >> 4) * 4 + r;
                red_m[row * 4 + wn] = mx;
                red_s[row * 4 + wn] = se;
            }
        }
    }
    __syncthreads();
    if (tid < 256) {
        float M = red_m[tid * 4], S = red_s[tid * 4];
        #pragma unroll
        for (int j = 1; j < 4; ++j) {
            const float m2 = red_m[tid * 4 + j], s2 = red_s[tid * 4 + j];
            const float Mn = fmaxf(M, m2);
            S = S * __expf(M - Mn) + s2 * __expf(m2 - Mn);
            M = Mn;
        }
        part_m[(arow0 + tid) * NCH + voc_blk] = M;
        part_s[(arow0 + tid) * NCH + voc_blk] = S;
    }
}

// ------------------------------------------------------- exact label dot ----
__global__ __launch_bounds__(256) void label_dot(
    const float* __restrict__ h, const float* __restrict__ W,
    const void* __restrict__ labels, float* __restrict__ lab_logit)
{
    bool is64 = true;
    #pragma unroll
    for (int i = 0; i < 8; ++i) {
        long long v = ((const long long*)labels)[i];
        if (v < 0 || v >= VOCAB) is64 = false;
    }
    const int t = blockIdx.x;
    const int lab = is64 ? (int)((const long long*)labels)[t]
                         : ((const int*)labels)[t];
    const float4* hp = (const float4*)(h + (long)t * DIM);
    const float4* wp = (const float4*)(W + (long)lab * DIM);
    float s = 0.f;
    #pragma unroll
    for (int j = 0; j < 2; ++j) {
        const float4 a = hp[threadIdx.x + j * 256];
        const float4 b = wp[threadIdx.x + j * 256];
        s += a.x * b.x + a.y * b.y + a.z * b.z + a.w * b.w;
    }
    #pragma unroll
    for (int msk = 1; msk < 64; msk <<= 1) s += __shfl_xor(s, msk, 64);
    __shared__ float ps[4];
    if ((threadIdx.x & 63) == 0) ps[threadIdx.x >> 6] = s;
    __syncthreads();
    if (threadIdx.x == 0) lab_logit[t] = ps[0] + ps[1] + ps[2] + ps[3];
}

// ---------------------------------------------------- per-token LSE merge ---
__global__ __launch_bounds__(256) void finalize_nll(
    const float* __restrict__ part_m, const float* __restrict__ part_s,
    const float* __restrict__ lab_logit, const float* __restrict__ wts,
    float* __restrict__ wnll)
{
    const int t    = blockIdx.x * 4 + (threadIdx.x >> 6);  // one wave / token
    const int lane = threadIdx.x & 63;
    float m = -3.4e38f, s = 0.f;
    #pragma unroll
    for (int j = 0; j < 4; ++j) {
        const int c = j * 64 + lane;
        const float pm = part_m[(long)t * NCH + c];
        const float ps = part_s[(long)t * NCH + c];
        const float M = fmaxf(m, pm);
        s = s * __expf(m - M) + ps * __expf(pm - M);
        m = M;
    }
    #pragma unroll
    for (int msk = 1; msk < 64; msk <<= 1) {
        const float om = __shfl_xor(m, msk, 64);
        const float os = __shfl_xor(s, msk, 64);
        const float M = fmaxf(m, om);
        s = s * __expf(m - M) + os * __expf(om - M);
        m = M;
    }
    if (lane == 0) {
        const float lse = m + logf(s);
        wnll[t] = wts[t] * (lse - lab_logit[t]);
    }
}

// -------------------------------------------------- deterministic reduce ----
__global__ __launch_bounds__(1024) void final_reduce(
    const float* __restrict__ wnll, const float* __restrict__ wts,
    float* __restrict__ out)
{
    float a = 0.f, b = 0.f;
    #pragma unroll
    for (int j = 0; j < 4; ++j) {
        const int i = threadIdx.x + j * 1024;
        a += wnll[i];
        b += wts[i];
    }
    #pragma unroll
    for (int msk = 1; msk < 64; msk <<= 1) {
        a += __shfl_xor(a, msk, 64);
        b += __shfl_xor(b, msk, 64);
    }
    __shared__ float pa[16], pb[16];
    if ((threadIdx.x & 63) == 0) {
        pa[threadIdx.x >> 6] = a;
        pb[threadIdx.x >> 6] = b;
    }
    __syncthreads();
    if (threadIdx.x == 0) {
        float A = 0.f, B = 0.f;
        #pragma unroll
        for (int i = 0; i < 16; ++i) { A += pa[i]; B += pb[i]; }
        out[0] = A / B;
    }
}

// ----------------------------------------------------------------- launch ---
extern "C" void kernel_launch(void* const* d_in, const int* in_sizes, int n_in,
                              void* d_out, int out_size, void* d_ws, size_t ws_size,
                              hipStream_t stream)
{
    const float* h      = (const float*)d_in[0];
    const void*  labels = d_in[1];
    const float* wts    = (const float*)d_in[2];
    const float* W      = (const float*)d_in[3];
    float* out = (float*)d_out;

    char* ws = (char*)d_ws;
    unsigned short* h_bf      = (unsigned short*)(ws);                 // 16 MB
    float*          part_m    = (float*)(ws + (16u << 20));            //  4 MB
    float*          part_s    = (float*)(ws + (24u << 20));            //  4 MB
    float*          lab_logit = (float*)(ws + (32u << 20));            // 16 KB
    float*          wnll      = (float*)(ws + (32u << 20) + 16384);    // 16 KB

    // 0) h -> bf16 (one small launch; W converts inside the GEMM)
    convert_f32_bf16<<<(N_TOK * DIM) / (256 * 8), 256, 0, stream>>>(
        h, h_bf, (long)N_TOK * DIM);

    // 1) single fused GEMM/convert/LSE launch over the whole vocab
    gemm_lse<<<NTB * NCH, 512, 0, stream>>>(h_bf, W, part_m, part_s);

    // 2) exact label logits (fp32)
    label_dot<<<N_TOK, 256, 0, stream>>>(h, W, labels, lab_logit);

    // 3) per-token LSE merge -> w*nll
    finalize_nll<<<N_TOK / 4, 256, 0, stream>>>(part_m, part_s, lab_logit,
                                                wts, wnll);

    // 4) weighted mean
    final_reduce<<<1, 1024, 0, stream>>>(wnll, wts, out);
}